// Round 1
// baseline (161.114 us; speedup 1.0000x reference)
//
#include <hip/hip_runtime.h>
#include <hip/hip_bf16.h>

typedef unsigned short ushort_t;
typedef __attribute__((ext_vector_type(8))) short s16x8;
typedef __attribute__((ext_vector_type(4))) float f32x4;

#define NB 8192
#define ND 128
#define LDP 136   // padded LDS stride in bf16 elements (272B: 2-way bank alias = free, 16B aligned)
#define EPS 1e-8f
#define MARGIN 1.0f

__device__ __forceinline__ unsigned f2u(float f) {
    unsigned u = __float_as_uint(f);
    return (u & 0x80000000u) ? ~u : (u | 0x80000000u);
}
__device__ __forceinline__ float u2f(unsigned u) {
    return (u & 0x80000000u) ? __uint_as_float(u & 0x7fffffffu) : __uint_as_float(~u);
}

// ---- kernel 1: f32 -> bf16 convert, row squared-norms, init atomic sentinels ----
__global__ void prep_kernel(const float* __restrict__ E,
                            ushort_t* __restrict__ Ebf,
                            float* __restrict__ sqA,
                            unsigned* __restrict__ posU,
                            unsigned* __restrict__ negU) {
    const int tid  = threadIdx.x;
    const int lane = tid & 63;
    const int row  = blockIdx.x * 4 + (tid >> 6);   // 4 rows (waves) per block

    const float2 v = reinterpret_cast<const float2*>(E + row * ND)[lane];
    __hip_bfloat16 b0 = __float2bfloat16(v.x);
    __hip_bfloat16 b1 = __float2bfloat16(v.y);
    ushort_t2_t: ;
    ushort_t pack[2];
    pack[0] = *reinterpret_cast<ushort_t*>(&b0);
    pack[1] = *reinterpret_cast<ushort_t*>(&b1);
    *reinterpret_cast<uint*>(&Ebf[row * ND + lane * 2]) = *reinterpret_cast<uint*>(pack);

    float ss = v.x * v.x + v.y * v.y;
    #pragma unroll
    for (int off = 32; off; off >>= 1) ss += __shfl_down(ss, off, 64);
    if (lane == 0) sqA[row] = ss;

    const int gid = blockIdx.x * 256 + tid;
    if (gid < NB) {
        posU[gid] = f2u(-__builtin_inff());   // "no positive seen"
        negU[gid] = f2u(__builtin_inff());    // "no negative seen"
    }
}

// ---- kernel 2: fused Gram tile + hardest-pos/neg reduction ----
__global__ __launch_bounds__(256, 2) void triplet_gemm(
        const ushort_t* __restrict__ Ebf,
        const float* __restrict__ sqA,
        const int* __restrict__ labels,
        unsigned* __restrict__ posU,
        unsigned* __restrict__ negU) {
    __shared__ __align__(16) ushort_t As[128 * LDP];
    __shared__ __align__(16) ushort_t Bs[128 * LDP];

    const int bx = blockIdx.x;             // col tile
    const int by = blockIdx.y;             // row tile
    const int rowBase = by * 128, colBase = bx * 128;
    const int tid  = threadIdx.x;
    const int lane = tid & 63;
    const int w    = tid >> 6;
    const int wr = w >> 1, wc = w & 1;     // 2x2 wave grid, 64x64 each

    // --- stage A and B tiles (whole K=128) into padded LDS ---
    {
        const uint4* gA = reinterpret_cast<const uint4*>(Ebf + rowBase * ND);
        const uint4* gB = reinterpret_cast<const uint4*>(Ebf + colBase * ND);
        #pragma unroll
        for (int it = 0; it < 8; ++it) {
            int c  = tid + it * 256;       // 16B chunk id, 0..2047
            int r  = c >> 4;               // row in tile
            int cc = c & 15;               // chunk within row
            uint4 va = gA[c];
            uint4 vb = gB[c];
            *reinterpret_cast<uint4*>(&As[r * LDP + cc * 8]) = va;
            *reinterpret_cast<uint4*>(&Bs[r * LDP + cc * 8]) = vb;
        }
    }
    __syncthreads();

    const int fr = lane & 15;              // fragment row/col index
    const int fg = lane >> 4;              // k-group / row-group

    f32x4 acc[4][4] = {};
    const int rb = wr * 64, cb = wc * 64;

    #pragma unroll
    for (int ks = 0; ks < 4; ++ks) {
        s16x8 a[4], b[4];
        #pragma unroll
        for (int mi = 0; mi < 4; ++mi)
            a[mi] = *reinterpret_cast<const s16x8*>(&As[(rb + mi * 16 + fr) * LDP + ks * 32 + fg * 8]);
        #pragma unroll
        for (int ni = 0; ni < 4; ++ni)
            b[ni] = *reinterpret_cast<const s16x8*>(&Bs[(cb + ni * 16 + fr) * LDP + ks * 32 + fg * 8]);
        #pragma unroll
        for (int mi = 0; mi < 4; ++mi)
            #pragma unroll
            for (int ni = 0; ni < 4; ++ni)
                acc[mi][ni] = __builtin_amdgcn_mfma_f32_16x16x32_bf16(a[mi], b[ni], acc[mi][ni], 0, 0, 0);
    }

    // --- fused epilogue: s = sq_j - 2*dot; track hardest pos (max) / neg (min) per row ---
    int gcol[4]; int labC[4]; float sqC[4];
    #pragma unroll
    for (int ni = 0; ni < 4; ++ni) {
        gcol[ni] = colBase + cb + ni * 16 + fr;
        labC[ni] = labels[gcol[ni]];
        sqC[ni]  = sqA[gcol[ni]];
    }
    const bool blockDiag = (bx == by);
    const float NEG_INF = -__builtin_inff();
    const float POS_INF =  __builtin_inff();

    #pragma unroll
    for (int mi = 0; mi < 4; ++mi) {
        const int grow0 = rowBase + rb + mi * 16 + fg * 4;
        #pragma unroll
        for (int reg = 0; reg < 4; ++reg) {
            const int grow = grow0 + reg;
            const int labR = labels[grow];
            float pv = NEG_INF, nv = POS_INF;
            #pragma unroll
            for (int ni = 0; ni < 4; ++ni) {
                float s  = fmaf(-2.0f, acc[mi][ni][reg], sqC[ni]);
                bool eq  = (labR == labC[ni]);
                bool posOk = eq && (!blockDiag || (grow != gcol[ni]));
                pv = fmaxf(pv, posOk ? s : NEG_INF);
                nv = fminf(nv, eq ? POS_INF : s);
            }
            // reduce across the 16-lane (column) group
            #pragma unroll
            for (int off = 1; off < 16; off <<= 1) {
                pv = fmaxf(pv, __shfl_xor(pv, off, 64));
                nv = fminf(nv, __shfl_xor(nv, off, 64));
            }
            if (fr == 0) {
                atomicMax(&posU[grow], f2u(pv));
                atomicMin(&negU[grow], f2u(nv));
            }
        }
    }
}

// ---- kernel 3: per-row distances, loss mean, valid count ----
__global__ void finalize_kernel(const float* __restrict__ sqA,
                                const unsigned* __restrict__ posU,
                                const unsigned* __restrict__ negU,
                                float* __restrict__ out) {
    __shared__ float sl[4];
    __shared__ float sc[4];
    const int tid = threadIdx.x;
    const int lane = tid & 63;
    const int w = tid >> 6;
    const unsigned PINIT = f2u(-__builtin_inff());
    const unsigned NINIT = f2u(__builtin_inff());

    float lsum = 0.f, csum = 0.f;
    for (int i = tid; i < NB; i += 256) {
        unsigned pu = posU[i], nu = negU[i];
        bool valid = (pu != PINIT) && (nu != NINIT);
        float pd = sqrtf(fmaxf(sqA[i] + u2f(pu), 0.f) + EPS);
        float nd = sqrtf(fmaxf(sqA[i] + u2f(nu), 0.f) + EPS);
        float l  = fmaxf(pd - nd + MARGIN, 0.f);
        if (valid) { lsum += l; csum += 1.f; }
    }
    #pragma unroll
    for (int off = 32; off; off >>= 1) {
        lsum += __shfl_down(lsum, off, 64);
        csum += __shfl_down(csum, off, 64);
    }
    if (lane == 0) { sl[w] = lsum; sc[w] = csum; }
    __syncthreads();
    if (tid == 0) {
        float L = 0.f, C = 0.f;
        #pragma unroll
        for (int k = 0; k < 4; ++k) { L += sl[k]; C += sc[k]; }
        out[0] = (C > 0.f) ? (L / C) : 0.f;
        out[1] = C;
    }
}

extern "C" void kernel_launch(void* const* d_in, const int* in_sizes, int n_in,
                              void* d_out, int out_size, void* d_ws, size_t ws_size,
                              hipStream_t stream) {
    const float* E      = (const float*)d_in[0];
    const int*   labels = (const int*)d_in[1];
    float*       out    = (float*)d_out;

    char* ws = (char*)d_ws;
    ushort_t* Ebf  = (ushort_t*)ws;                                   // 2 MiB
    float*    sqA  = (float*)(ws + (size_t)NB * ND * 2);              // 32 KiB
    unsigned* posU = (unsigned*)(ws + (size_t)NB * ND * 2 + NB * 4);  // 32 KiB
    unsigned* negU = (unsigned*)(ws + (size_t)NB * ND * 2 + NB * 8);  // 32 KiB

    prep_kernel<<<NB / 4, 256, 0, stream>>>(E, Ebf, sqA, posU, negU);

    dim3 grid(NB / 128, NB / 128);
    triplet_gemm<<<grid, 256, 0, stream>>>(Ebf, sqA, labels, posU, negU);

    finalize_kernel<<<1, 256, 0, stream>>>(sqA, posU, negU, out);
}

// Round 2
// 160.294 us; speedup vs baseline: 1.0051x; 1.0051x over previous
//
#include <hip/hip_runtime.h>
#include <hip/hip_bf16.h>

typedef unsigned short ushort_t;
typedef __attribute__((ext_vector_type(8))) short s16x8;
typedef __attribute__((ext_vector_type(4))) float f32x4;

#define NB 8192
#define ND 128
#define NT 8            // B tiles per chunk
#define CHUNK 1024      // columns per block
#define EPS 1e-8f
#define MARGIN 1.0f

__device__ __forceinline__ unsigned f2u(float f) {
    unsigned u = __float_as_uint(f);
    return (u & 0x80000000u) ? ~u : (u | 0x80000000u);
}
__device__ __forceinline__ float u2f(unsigned u) {
    return (u & 0x80000000u) ? __uint_as_float(u & 0x7fffffffu) : __uint_as_float(~u);
}

typedef const __attribute__((address_space(1))) void* gptr_t;
typedef __attribute__((address_space(3))) void* lptr_t;
__device__ __forceinline__ void gll16(const void* g, void* l) {
    __builtin_amdgcn_global_load_lds((gptr_t)g, (lptr_t)l, 16, 0, 0);
}

// stage one 128x128 bf16 tile global->LDS, 16B/lane, XOR-swizzled via source
// LDS[row][slot] = G[row][slot ^ (row&7)]  (slot = 16B unit, 16 slots/row)
__device__ __forceinline__ void stage_tile(const ushort_t* __restrict__ gbase,
                                           ushort_t* lbase, int tid, int w) {
    #pragma unroll
    for (int it = 0; it < 8; ++it) {
        const int c = it * 256 + tid;         // 16B chunk id 0..2047
        const int r = c >> 4;
        const int s = c & 15;
        const int ss = s ^ (r & 7);           // pre-swizzled source slot
        const ushort_t* g = gbase + r * ND + ss * 8;
        ushort_t* l = lbase + (it * 256 + w * 64) * 8;   // wave-uniform dest
        gll16(g, l);
    }
}

// ---- kernel 1: f32->bf16, row squared-norms, init sentinels + accumulators ----
__global__ void prep_kernel(const float* __restrict__ E,
                            ushort_t* __restrict__ Ebf,
                            float* __restrict__ sqA,
                            unsigned* __restrict__ posU,
                            unsigned* __restrict__ negU,
                            float* __restrict__ acc2) {
    const int tid  = threadIdx.x;
    const int lane = tid & 63;
    const int row  = blockIdx.x * 4 + (tid >> 6);

    const float2 v = reinterpret_cast<const float2*>(E + (size_t)row * ND)[lane];
    __hip_bfloat16 b0 = __float2bfloat16(v.x);
    __hip_bfloat16 b1 = __float2bfloat16(v.y);
    ushort_t pk[2] = { *reinterpret_cast<ushort_t*>(&b0), *reinterpret_cast<ushort_t*>(&b1) };
    *reinterpret_cast<uint*>(&Ebf[(size_t)row * ND + lane * 2]) = *reinterpret_cast<uint*>(pk);

    float ss = v.x * v.x + v.y * v.y;
    #pragma unroll
    for (int off = 32; off; off >>= 1) ss += __shfl_down(ss, off, 64);
    if (lane == 0) sqA[row] = ss;

    const int gid = blockIdx.x * 256 + tid;
    if (gid < NB) {
        posU[gid] = f2u(-__builtin_inff());
        negU[gid] = f2u(__builtin_inff());
    }
    if (blockIdx.x == 0 && tid < 2) acc2[tid] = 0.f;
}

// ---- kernel 2: A-in-registers, stream 8 B tiles, fold into pv/nv ----
__global__ __launch_bounds__(256, 2) void triplet_gemm(
        const ushort_t* __restrict__ Ebf,
        const float* __restrict__ sqAp,
        const int* __restrict__ labels,
        unsigned* __restrict__ posU,
        unsigned* __restrict__ negU) {
    __shared__ __align__(16) ushort_t buf[2][128 * 128];
    __shared__ __align__(16) int   ldsLab[CHUNK];
    __shared__ __align__(16) float ldsSq[CHUNK];

    const int tid = threadIdx.x, lane = tid & 63, w = tid >> 6;
    const int wr = w >> 1, wc = w & 1;
    const int fr = lane & 15, fg = lane >> 4;
    const int rowBase = blockIdx.x * 128;
    const int chunkBase = blockIdx.y * CHUNK;
    const int rb = wr * 64, cb = wc * 64;

    // prologue: stage A tile -> buf0, chunk labels/sq -> LDS; preload row labels
    stage_tile(Ebf + (size_t)rowBase * ND, &buf[0][0], tid, w);
    gll16(labels + chunkBase + tid * 4, ldsLab + w * 256);
    gll16(sqAp   + chunkBase + tid * 4, ldsSq  + w * 256);

    int labR[4][4];
    #pragma unroll
    for (int mi = 0; mi < 4; ++mi)
        #pragma unroll
        for (int reg = 0; reg < 4; ++reg)
            labR[mi][reg] = labels[rowBase + rb + mi * 16 + fg * 4 + reg];

    int swByte[4];
    #pragma unroll
    for (int ks = 0; ks < 4; ++ks) swByte[ks] = ((ks * 4 + fg) ^ (fr & 7)) * 16;

    asm volatile("s_waitcnt vmcnt(0)" ::: "memory");
    __builtin_amdgcn_s_barrier();

    // issue B tile0 -> buf1 while we read A fragments from buf0
    stage_tile(Ebf + (size_t)chunkBase * ND, &buf[1][0], tid, w);

    s16x8 a[4][4];
    {
        const char* p0 = (const char*)&buf[0][0];
        #pragma unroll
        for (int ks = 0; ks < 4; ++ks)
            #pragma unroll
            for (int mi = 0; mi < 4; ++mi)
                a[ks][mi] = *reinterpret_cast<const s16x8*>(
                    p0 + (rb + mi * 16 + fr) * 256 + swByte[ks]);
    }
    asm volatile("s_waitcnt lgkmcnt(0)" ::: "memory");
    __builtin_amdgcn_sched_barrier(0);
    __builtin_amdgcn_s_barrier();          // buf0 now reusable

    const float NEG_INF = -__builtin_inff(), POS_INF = __builtin_inff();
    f32x4 pv[4], nv[4];
    #pragma unroll
    for (int mi = 0; mi < 4; ++mi) {
        pv[mi] = f32x4{NEG_INF, NEG_INF, NEG_INF, NEG_INF};
        nv[mi] = f32x4{POS_INF, POS_INF, POS_INF, POS_INF};
    }
    const f32x4 zf = {0.f, 0.f, 0.f, 0.f};

    #pragma unroll
    for (int t = 0; t < NT; ++t) {
        ushort_t* cur = &buf[1 ^ (t & 1)][0];
        ushort_t* nxt = &buf[t & 1][0];
        if (t + 1 < NT) {
            stage_tile(Ebf + (size_t)(chunkBase + (t + 1) * 128) * ND, nxt, tid, w);
            asm volatile("s_waitcnt vmcnt(8)" ::: "memory");   // tile t landed; t+1 in flight
        } else {
            asm volatile("s_waitcnt vmcnt(0)" ::: "memory");
        }
        __builtin_amdgcn_s_barrier();

        int labC[4]; float sqC[4];
        #pragma unroll
        for (int ni = 0; ni < 4; ++ni) {
            labC[ni] = ldsLab[t * 128 + cb + ni * 16 + fr];
            sqC[ni]  = ldsSq [t * 128 + cb + ni * 16 + fr];
        }

        const char* cp = (const char*)cur;
        #pragma unroll
        for (int ni = 0; ni < 4; ++ni) {
            s16x8 b[4];
            #pragma unroll
            for (int ks = 0; ks < 4; ++ks)
                b[ks] = *reinterpret_cast<const s16x8*>(
                    cp + (cb + ni * 16 + fr) * 256 + swByte[ks]);
            #pragma unroll
            for (int mi = 0; mi < 4; ++mi) {
                f32x4 acc = __builtin_amdgcn_mfma_f32_16x16x32_bf16(a[0][mi], b[0], zf, 0, 0, 0);
                acc = __builtin_amdgcn_mfma_f32_16x16x32_bf16(a[1][mi], b[1], acc, 0, 0, 0);
                acc = __builtin_amdgcn_mfma_f32_16x16x32_bf16(a[2][mi], b[2], acc, 0, 0, 0);
                acc = __builtin_amdgcn_mfma_f32_16x16x32_bf16(a[3][mi], b[3], acc, 0, 0, 0);
                #pragma unroll
                for (int reg = 0; reg < 4; ++reg) {
                    float sv = fmaf(-2.0f, acc[reg], sqC[ni]);
                    bool eq = (labR[mi][reg] == labC[ni]);
                    pv[mi][reg] = fmaxf(pv[mi][reg], eq ? sv : NEG_INF);
                    nv[mi][reg] = fminf(nv[mi][reg], eq ? POS_INF : sv);
                }
            }
        }
        asm volatile("s_waitcnt lgkmcnt(0)" ::: "memory");
        __builtin_amdgcn_sched_barrier(0);
        __builtin_amdgcn_s_barrier();      // tile t's buffer reusable
    }

    // epilogue: reduce over the 16 fr-lanes, one atomic pair per row
    #pragma unroll
    for (int mi = 0; mi < 4; ++mi) {
        #pragma unroll
        for (int reg = 0; reg < 4; ++reg) {
            float p = pv[mi][reg], n = nv[mi][reg];
            #pragma unroll
            for (int off = 1; off < 16; off <<= 1) {
                p = fmaxf(p, __shfl_xor(p, off, 64));
                n = fminf(n, __shfl_xor(n, off, 64));
            }
            if (fr == 0) {
                const int grow = rowBase + rb + mi * 16 + fg * 4 + reg;
                atomicMax(&posU[grow], f2u(p));
                atomicMin(&negU[grow], f2u(n));
            }
        }
    }
}

// ---- kernel 3a: per-row loss, block-reduce, atomic accumulate ----
__global__ void finalize_partial(const float* __restrict__ sqA,
                                 const unsigned* __restrict__ posU,
                                 const unsigned* __restrict__ negU,
                                 float* __restrict__ acc2) {
    __shared__ float sl[4], sc[4];
    const int tid = threadIdx.x, lane = tid & 63, w = tid >> 6;
    const int i = blockIdx.x * 256 + tid;
    const unsigned PINIT = f2u(-__builtin_inff());
    const unsigned NINIT = f2u(__builtin_inff());

    unsigned pu = posU[i], nu = negU[i];
    bool valid = (pu != PINIT) && (nu != NINIT);
    float sq = sqA[i];
    float pd = sqrtf(fmaxf(sq + u2f(pu), 0.f) + EPS);
    float nd = sqrtf(fmaxf(sq + u2f(nu), 0.f) + EPS);
    float l  = fmaxf(pd - nd + MARGIN, 0.f);
    float lv = valid ? l : 0.f;
    float cv = valid ? 1.f : 0.f;
    #pragma unroll
    for (int off = 32; off; off >>= 1) {
        lv += __shfl_down(lv, off, 64);
        cv += __shfl_down(cv, off, 64);
    }
    if (lane == 0) { sl[w] = lv; sc[w] = cv; }
    __syncthreads();
    if (tid == 0) {
        atomicAdd(&acc2[0], sl[0] + sl[1] + sl[2] + sl[3]);
        atomicAdd(&acc2[1], sc[0] + sc[1] + sc[2] + sc[3]);
    }
}

// ---- kernel 3b: write outputs ----
__global__ void finalize_write(const float* __restrict__ acc2, float* __restrict__ out) {
    if (threadIdx.x == 0) {
        float C = acc2[1];
        out[0] = (C > 0.f) ? (acc2[0] / C) : 0.f;
        out[1] = C;
    }
}

extern "C" void kernel_launch(void* const* d_in, const int* in_sizes, int n_in,
                              void* d_out, int out_size, void* d_ws, size_t ws_size,
                              hipStream_t stream) {
    const float* E      = (const float*)d_in[0];
    const int*   labels = (const int*)d_in[1];
    float*       out    = (float*)d_out;

    char* ws = (char*)d_ws;
    ushort_t* Ebf  = (ushort_t*)ws;                                   // 2 MiB
    float*    sqA  = (float*)(ws + (size_t)NB * ND * 2);              // 32 KiB
    unsigned* posU = (unsigned*)(ws + (size_t)NB * ND * 2 + NB * 4);  // 32 KiB
    unsigned* negU = (unsigned*)(ws + (size_t)NB * ND * 2 + NB * 8);  // 32 KiB
    float*    acc2 = (float*)(ws + (size_t)NB * ND * 2 + NB * 12);    // 8 B

    prep_kernel<<<NB / 4, 256, 0, stream>>>(E, Ebf, sqA, posU, negU, acc2);

    dim3 grid(NB / 128, NB / CHUNK);
    triplet_gemm<<<grid, 256, 0, stream>>>(Ebf, sqA, labels, posU, negU);

    finalize_partial<<<NB / 256, 256, 0, stream>>>(sqA, posU, negU, acc2);
    finalize_write<<<1, 64, 0, stream>>>(acc2, out);
}

// Round 3
// 46.374 us; speedup vs baseline: 3.4742x; 3.4565x over previous
//
#include <hip/hip_runtime.h>
#include <hip/hip_bf16.h>

typedef unsigned short ushort_t;
typedef __attribute__((ext_vector_type(8))) short s16x8;
typedef __attribute__((ext_vector_type(4))) float f32x4;

#define NB 8192
#define ND 128
#define BM 64              // rows per block stripe
#define TCOLS 64           // cols per B tile
#define CHUNK 1024         // cols per block
#define NT (CHUNK/TCOLS)   // 16 tiles
#define NCHUNK (NB/CHUNK)  // 8
#define EPS 1e-8f
#define MARGIN 1.0f

typedef const __attribute__((address_space(1))) void* gptr_t;
typedef __attribute__((address_space(3))) void* lptr_t;
__device__ __forceinline__ void gll16(const void* g, void* l) {
    __builtin_amdgcn_global_load_lds((gptr_t)g, (lptr_t)l, 16, 0, 0);
}

// stage one 64-row x 128-col bf16 tile (16 KB) global->LDS, source-swizzled:
// LDS[r][s] = G[r][s ^ (r&7)]   (s = 16B slot, 16 slots/row)
__device__ __forceinline__ void stage64(const ushort_t* __restrict__ g,
                                        ushort_t* l, int tid, int w) {
    #pragma unroll
    for (int it = 0; it < 4; ++it) {
        const int c = it * 256 + tid;          // 16B chunk 0..1023
        const int r = c >> 4, s = c & 15;
        const int ss = s ^ (r & 7);
        gll16(g + r * ND + ss * 8, l + (it * 256 + w * 64) * 8);
    }
}

// ---- kernel 1: f32 -> bf16 + row squared-norms ----
__global__ void prep_kernel(const float* __restrict__ E,
                            ushort_t* __restrict__ Ebf,
                            float* __restrict__ sqA) {
    const int tid  = threadIdx.x;
    const int lane = tid & 63;
    const int row  = blockIdx.x * 4 + (tid >> 6);

    const float2 v = reinterpret_cast<const float2*>(E + (size_t)row * ND)[lane];
    __hip_bfloat16 b0 = __float2bfloat16(v.x);
    __hip_bfloat16 b1 = __float2bfloat16(v.y);
    ushort_t pk[2] = { *reinterpret_cast<ushort_t*>(&b0), *reinterpret_cast<ushort_t*>(&b1) };
    *reinterpret_cast<uint*>(&Ebf[(size_t)row * ND + lane * 2]) = *reinterpret_cast<uint*>(pk);

    float ss = v.x * v.x + v.y * v.y;
    #pragma unroll
    for (int off = 32; off; off >>= 1) ss += __shfl_down(ss, off, 64);
    if (lane == 0) sqA[row] = ss;
}

// ---- kernel 2: Gram stripe x chunk, fold into hardest-pos/neg, store partials ----
__global__ __launch_bounds__(256, 2) void triplet_gemm(
        const ushort_t* __restrict__ Ebf,
        const float* __restrict__ sqAp,
        const int* __restrict__ labels,
        float* __restrict__ pvPart,
        float* __restrict__ nvPart) {
    __shared__ __align__(16) ushort_t As[BM * ND];          // 16 KB
    __shared__ __align__(16) ushort_t Bb[2][TCOLS * ND];    // 32 KB
    __shared__ __align__(16) int   ldsLab[CHUNK];           // 4 KB
    __shared__ __align__(16) float ldsSq[CHUNK];            // 4 KB
    __shared__ __align__(16) float pvRed[2][BM][16];        // 8 KB
    __shared__ __align__(16) float nvRed[2][BM][16];        // 8 KB

    const int tid = threadIdx.x, lane = tid & 63, w = tid >> 6;
    const int wr = w >> 1, wc = w & 1;
    const int fr = lane & 15, fg = lane >> 4;
    const int rowBase = blockIdx.x * BM;
    const int chunkBase = blockIdx.y * CHUNK;
    const int rb = wr * 32, cb = wc * 32;

    // prologue: stage A stripe + B tile0 + labels/sq
    stage64(Ebf + (size_t)rowBase * ND, As, tid, w);
    stage64(Ebf + (size_t)chunkBase * ND, &Bb[0][0], tid, w);
    gll16(labels + chunkBase + tid * 4, (int*)ldsLab + w * 256);
    gll16(sqAp   + chunkBase + tid * 4, (float*)ldsSq + w * 256);

    int labR[2][4];
    #pragma unroll
    for (int mi = 0; mi < 2; ++mi)
        #pragma unroll
        for (int reg = 0; reg < 4; ++reg)
            labR[mi][reg] = labels[rowBase + rb + mi * 16 + fg * 4 + reg];

    int swByte[4];
    #pragma unroll
    for (int ks = 0; ks < 4; ++ks) swByte[ks] = ((ks * 4 + fg) ^ (fr & 7)) * 16;

    asm volatile("s_waitcnt vmcnt(0)" ::: "memory");
    __builtin_amdgcn_s_barrier();
    __builtin_amdgcn_sched_barrier(0);

    // hoist A fragments (reused by all 16 tiles): 8 frags = 32 VGPR
    s16x8 a[4][2];
    {
        const char* ap = (const char*)As;
        #pragma unroll
        for (int ks = 0; ks < 4; ++ks)
            #pragma unroll
            for (int mi = 0; mi < 2; ++mi)
                a[ks][mi] = *reinterpret_cast<const s16x8*>(
                    ap + (rb + mi * 16 + fr) * 256 + swByte[ks]);
    }

    const float NEG_INF = -__builtin_inff(), POS_INF = __builtin_inff();
    f32x4 pv[2], nv[2];
    #pragma unroll
    for (int mi = 0; mi < 2; ++mi) {
        pv[mi] = f32x4{NEG_INF, NEG_INF, NEG_INF, NEG_INF};
        nv[mi] = f32x4{POS_INF, POS_INF, POS_INF, POS_INF};
    }

    auto tile_step = [&](int t, const ushort_t* cur, ushort_t* nxt) {
        if (t + 1 < NT)
            stage64(Ebf + (size_t)(chunkBase + (t + 1) * TCOLS) * ND, nxt, tid, w);

        int labC[2]; float sqC[2];
        #pragma unroll
        for (int ni = 0; ni < 2; ++ni) {
            labC[ni] = ldsLab[t * TCOLS + cb + ni * 16 + fr];
            sqC[ni]  = ldsSq [t * TCOLS + cb + ni * 16 + fr];
        }

        const char* cp = (const char*)cur;
        f32x4 acc[2][2];
        #pragma unroll
        for (int ks = 0; ks < 4; ++ks) {
            s16x8 b0 = *reinterpret_cast<const s16x8*>(cp + (cb +  0 + fr) * 256 + swByte[ks]);
            s16x8 b1 = *reinterpret_cast<const s16x8*>(cp + (cb + 16 + fr) * 256 + swByte[ks]);
            if (ks == 0) {
                const f32x4 zf = {0.f, 0.f, 0.f, 0.f};
                acc[0][0] = __builtin_amdgcn_mfma_f32_16x16x32_bf16(a[0][0], b0, zf, 0, 0, 0);
                acc[0][1] = __builtin_amdgcn_mfma_f32_16x16x32_bf16(a[0][0], b1, zf, 0, 0, 0);
                acc[1][0] = __builtin_amdgcn_mfma_f32_16x16x32_bf16(a[0][1], b0, zf, 0, 0, 0);
                acc[1][1] = __builtin_amdgcn_mfma_f32_16x16x32_bf16(a[0][1], b1, zf, 0, 0, 0);
            } else {
                acc[0][0] = __builtin_amdgcn_mfma_f32_16x16x32_bf16(a[ks][0], b0, acc[0][0], 0, 0, 0);
                acc[0][1] = __builtin_amdgcn_mfma_f32_16x16x32_bf16(a[ks][0], b1, acc[0][1], 0, 0, 0);
                acc[1][0] = __builtin_amdgcn_mfma_f32_16x16x32_bf16(a[ks][1], b0, acc[1][0], 0, 0, 0);
                acc[1][1] = __builtin_amdgcn_mfma_f32_16x16x32_bf16(a[ks][1], b1, acc[1][1], 0, 0, 0);
            }
        }

        #pragma unroll
        for (int mi = 0; mi < 2; ++mi)
            #pragma unroll
            for (int ni = 0; ni < 2; ++ni)
                #pragma unroll
                for (int reg = 0; reg < 4; ++reg) {
                    float sv = fmaf(-2.0f, acc[mi][ni][reg], sqC[ni]);
                    bool eq = (labR[mi][reg] == labC[ni]);
                    pv[mi][reg] = fmaxf(pv[mi][reg], eq ? sv : NEG_INF);
                    nv[mi][reg] = fminf(nv[mi][reg], eq ? POS_INF : sv);
                }

        asm volatile("s_waitcnt vmcnt(0) lgkmcnt(0)" ::: "memory");
        __builtin_amdgcn_sched_barrier(0);
        __builtin_amdgcn_s_barrier();
        __builtin_amdgcn_sched_barrier(0);
    };

    for (int tt = 0; tt < NT; tt += 2) {
        tile_step(tt,     &Bb[0][0], &Bb[1][0]);
        tile_step(tt + 1, &Bb[1][0], &Bb[0][0]);
    }

    // epilogue: LDS transpose-reduce across 16 fr-lanes and both wc waves
    #pragma unroll
    for (int mi = 0; mi < 2; ++mi)
        #pragma unroll
        for (int reg = 0; reg < 4; ++reg) {
            const int rbk = rb + mi * 16 + fg * 4 + reg;
            pvRed[wc][rbk][fr] = pv[mi][reg];
            nvRed[wc][rbk][fr] = nv[mi][reg];
        }
    __syncthreads();

    if (tid < BM) {
        float p = NEG_INF, n = POS_INF;
        #pragma unroll
        for (int j = 0; j < 16; ++j) {
            p = fmaxf(p, fmaxf(pvRed[0][tid][j], pvRed[1][tid][j]));
            n = fminf(n, fminf(nvRed[0][tid][j], nvRed[1][tid][j]));
        }
        pvPart[(size_t)blockIdx.y * NB + rowBase + tid] = p;
        nvPart[(size_t)blockIdx.y * NB + rowBase + tid] = n;
    }
}

// ---- kernel 3: single-block deterministic finalize ----
__global__ void finalize_kernel(const float* __restrict__ sqA,
                                const float* __restrict__ pvPart,
                                const float* __restrict__ nvPart,
                                float* __restrict__ out) {
    __shared__ float sl[16], sc[16];
    const int tid = threadIdx.x, lane = tid & 63, w = tid >> 6;
    const float NEG_INF = -__builtin_inff(), POS_INF = __builtin_inff();

    float lsum = 0.f, csum = 0.f;
    #pragma unroll
    for (int k = 0; k < NB / 1024; ++k) {
        const int i = k * 1024 + tid;
        float pv = NEG_INF, nv = POS_INF;
        #pragma unroll
        for (int p = 0; p < NCHUNK; ++p) {
            pv = fmaxf(pv, pvPart[(size_t)p * NB + i]);
            nv = fminf(nv, nvPart[(size_t)p * NB + i]);
        }
        bool valid = (pv != NEG_INF) && (nv != POS_INF);
        float sq = sqA[i];
        float pd = sqrtf(fmaxf(sq + pv, 0.f) + EPS);
        float nd = sqrtf(fmaxf(sq + nv, 0.f) + EPS);
        float l  = fmaxf(pd - nd + MARGIN, 0.f);
        if (valid) { lsum += l; csum += 1.f; }
    }
    #pragma unroll
    for (int off = 32; off; off >>= 1) {
        lsum += __shfl_down(lsum, off, 64);
        csum += __shfl_down(csum, off, 64);
    }
    if (lane == 0) { sl[w] = lsum; sc[w] = csum; }
    __syncthreads();
    if (tid == 0) {
        float L = 0.f, C = 0.f;
        #pragma unroll
        for (int k = 0; k < 16; ++k) { L += sl[k]; C += sc[k]; }
        out[0] = (C > 0.f) ? (L / C) : 0.f;
        out[1] = C;
    }
}

extern "C" void kernel_launch(void* const* d_in, const int* in_sizes, int n_in,
                              void* d_out, int out_size, void* d_ws, size_t ws_size,
                              hipStream_t stream) {
    const float* E      = (const float*)d_in[0];
    const int*   labels = (const int*)d_in[1];
    float*       out    = (float*)d_out;

    char* ws = (char*)d_ws;
    ushort_t* Ebf    = (ushort_t*)ws;                                // 2 MiB
    float*    sqA    = (float*)(ws + (size_t)NB * ND * 2);           // 32 KiB
    float*    pvPart = (float*)(ws + (size_t)NB * ND * 2 + NB * 4);  // 256 KiB
    float*    nvPart = (float*)(ws + (size_t)NB * ND * 2 + NB * 4 + (size_t)NCHUNK * NB * 4);

    prep_kernel<<<NB / 4, 256, 0, stream>>>(E, Ebf, sqA);

    dim3 grid(NB / BM, NCHUNK);
    triplet_gemm<<<grid, 256, 0, stream>>>(Ebf, sqA, labels, pvPart, nvPart);

    finalize_kernel<<<1, 1024, 0, stream>>>(sqA, pvPart, nvPart, out);
}